// Round 1
// baseline (508.863 us; speedup 1.0000x reference)
//
#include <hip/hip_runtime.h>
#include <hip/hip_bf16.h>

typedef short bf16x8 __attribute__((ext_vector_type(8)));
typedef float f32x4 __attribute__((ext_vector_type(4)));
typedef __attribute__((address_space(1))) const void gconst_t;
typedef __attribute__((address_space(3))) void lds_t;

#define DEVI __device__ __forceinline__

constexpr int BATCH   = 8192;
constexpr int IN_DIM  = 1024;
constexpr int HID     = 4096;
constexpr int OUT_DIM = 1024;
constexpr int NE      = 3;

// ---- workspace layout (bytes) ----
constexpr size_t XBF_OFF  = 0;                         // x bf16: 8192*1024*2      = 16 MB
constexpr size_t W1T_OFF  = 16777216;                  // W1T bf16: 3*4096*1024*2  = 24 MB
constexpr size_t W2T_OFF  = W1T_OFF + 25165824;        // W2T bf16: 3*1024*4096*2  = 24 MB
constexpr size_t H_OFF    = W2T_OFF + 25165824;        // H bf16: 8192*4096*2      = 64 MB
constexpr size_t META_OFF = H_OFF + 67108864;          // counters + lists
// meta: counts[0..7], counters2[8..15], toklist[3*8192], selected[8192]

DEVI unsigned short f2bf(float f) {
  __hip_bfloat16 h = __float2bfloat16(f);
  return *reinterpret_cast<unsigned short*>(&h);
}

// ---- convert x to bf16 ----
__global__ __launch_bounds__(256) void cvt_x_kernel(const float* __restrict__ x,
                                                    unsigned short* __restrict__ xb) {
  const int total = BATCH * IN_DIM / 4;
  for (int i = blockIdx.x * 256 + threadIdx.x; i < total; i += gridDim.x * 256) {
    float4 v = ((const float4*)x)[i];
    ushort4 o;
    o.x = f2bf(v.x); o.y = f2bf(v.y); o.z = f2bf(v.z); o.w = f2bf(v.w);
    ((ushort4*)xb)[i] = o;
  }
}

// ---- transpose + convert weights: src f32 [R][C] -> dst bf16 [C][R], per expert (blockIdx.z) ----
__global__ __launch_bounds__(256) void transpose_cvt(const float* __restrict__ src,
                                                     unsigned short* __restrict__ dst,
                                                     int R, int C) {
  __shared__ float tile[64][65];
  const size_t bo = (size_t)blockIdx.z * R * C;
  src += bo; dst += bo;
  const int r0 = blockIdx.y * 64, c0 = blockIdx.x * 64;
  const int tr = threadIdx.x >> 4;          // 0..15
  const int tc = (threadIdx.x & 15) << 2;   // 0,4,...,60
#pragma unroll
  for (int i = 0; i < 4; i++) {
    int r = tr + i * 16;
    const float4 v = *(const float4*)(src + (size_t)(r0 + r) * C + (c0 + tc));
    tile[r][tc + 0] = v.x; tile[r][tc + 1] = v.y; tile[r][tc + 2] = v.z; tile[r][tc + 3] = v.w;
  }
  __syncthreads();
#pragma unroll
  for (int i = 0; i < 4; i++) {
    int c = tr + i * 16;  // output row = original col
    ushort4 o;
    o.x = f2bf(tile[tc + 0][c]);
    o.y = f2bf(tile[tc + 1][c]);
    o.z = f2bf(tile[tc + 2][c]);
    o.w = f2bf(tile[tc + 3][c]);
    *(ushort4*)(dst + (size_t)(c0 + c) * R + (r0 + tc)) = o;
  }
}

// ---- f32 router: rh = relu(x@W1r+b1r); logits = rh@W2r+b2r; argmax; bincount ----
__global__ __launch_bounds__(128) void router_kernel(
    const float* __restrict__ x, const float* __restrict__ w1, const float* __restrict__ b1,
    const float* __restrict__ w2, const float* __restrict__ b2,
    int* __restrict__ selected, int* __restrict__ counts) {
  __shared__ float xs[8][1024];
  __shared__ float rh[8][128];
  __shared__ float lg[8][3];
  const int t0 = blockIdx.x * 8;
  const int tid = threadIdx.x;
  {
    const float4* src = (const float4*)(x + (size_t)t0 * 1024);
    float4* dstv = (float4*)&xs[0][0];
    for (int i = tid; i < 8 * 1024 / 4; i += 128) dstv[i] = src[i];
  }
  __syncthreads();
  float acc[8];
#pragma unroll
  for (int t = 0; t < 8; t++) acc[t] = 0.f;
  for (int k = 0; k < 1024; k += 4) {
    float w0 = w1[(k + 0) * 128 + tid];
    float w1v = w1[(k + 1) * 128 + tid];
    float w2v = w1[(k + 2) * 128 + tid];
    float w3v = w1[(k + 3) * 128 + tid];
#pragma unroll
    for (int t = 0; t < 8; t++) {
      const float4 xv = *(const float4*)&xs[t][k];
      acc[t] = fmaf(xv.x, w0, acc[t]);
      acc[t] = fmaf(xv.y, w1v, acc[t]);
      acc[t] = fmaf(xv.z, w2v, acc[t]);
      acc[t] = fmaf(xv.w, w3v, acc[t]);
    }
  }
  const float bb = b1[tid];
#pragma unroll
  for (int t = 0; t < 8; t++) rh[t][tid] = fmaxf(acc[t] + bb, 0.f);
  __syncthreads();
  if (tid < 24) {
    int t = tid / 3, e = tid % 3;
    float s = b2[e];
    for (int j = 0; j < 128; j++) s = fmaf(rh[t][j], w2[j * 3 + e], s);
    lg[t][e] = s;
  }
  __syncthreads();
  if (tid < 8) {
    float l0 = lg[tid][0], l1 = lg[tid][1], l2 = lg[tid][2];
    int sel = 0; float m = l0;
    if (l1 > m) { m = l1; sel = 1; }
    if (l2 > m) { m = l2; sel = 2; }
    selected[t0 + tid] = sel;
    atomicAdd(&counts[sel], 1);
  }
}

// ---- bucket tokens by expert; emit routing_stats as f32 into d_out tail ----
__global__ __launch_bounds__(256) void bucket_kernel(
    const int* __restrict__ selected, int* __restrict__ counters2,
    int* __restrict__ toklist, const int* __restrict__ counts, float* __restrict__ tail) {
  int i = blockIdx.x * 256 + threadIdx.x;
  if (i < BATCH) {
    int e = selected[i];
    int slot = atomicAdd(&counters2[e], 1);
    toklist[e * BATCH + slot] = i;
  }
  if (blockIdx.x == 0 && threadIdx.x < NE) tail[threadIdx.x] = (float)counts[threadIdx.x];
}

// ---- grouped bf16 GEMM, 128x128 tile, BK=64, 4 waves, m97-style ----
// MODE 0: A = x_bf16 gathered via toklist, B = W1T[e] (4096x1024), out = relu(+b1) -> H bf16 (grouped rows)
// MODE 1: A = H (grouped rows),            B = W2T[e] (1024x4096), out = +b2 -> scatter f32 rows of d_out
template <int MODE>
__global__ __launch_bounds__(256, 2) void moe_gemm(
    const unsigned short* __restrict__ Abase, const unsigned short* __restrict__ Ball,
    const float* __restrict__ biasAll, unsigned short* __restrict__ Hout,
    float* __restrict__ Yout, const int* __restrict__ toklist, const int* __restrict__ counts) {
  constexpr int N = (MODE == 0) ? HID : OUT_DIM;
  constexpr int K = (MODE == 0) ? IN_DIM : HID;
  const int e = blockIdx.z;
  const int cnt = counts[e];
  const int m0 = blockIdx.x * 128;
  if (m0 >= cnt) return;
  const int n0 = blockIdx.y * 128;
  const int off_e = (e > 0 ? counts[0] : 0) + (e > 1 ? counts[1] : 0);
  const unsigned short* Bmat = Ball + (size_t)e * ((size_t)N * K);
  const float* bias = biasAll + (size_t)e * N;

  __shared__ unsigned short At[128 * 64];  // [row][k] rows of 128 B, XOR-swizzled storage
  __shared__ unsigned short Bt[128 * 64];  // rows are N-indices (B pre-transposed)

  const int tid = threadIdx.x;
  // staging precompute: 4 16B loads each for A and B; LDS dest is linear (o),
  // global source is pre-swizzled (p) so readers can apply the same XOR (G21).
  const unsigned short* aptr[4];
  const unsigned short* bptr[4];
  unsigned ldsoff[4];
#pragma unroll
  for (int l = 0; l < 4; l++) {
    unsigned o = l * 4096u + (unsigned)tid * 16u;
    unsigned p = o ^ (((o >> 7) & 7u) << 4);
    int row = (int)(p >> 7);
    int kel = (int)((p & 127u) >> 1);
    ldsoff[l] = o;
    bptr[l] = Bmat + (size_t)(n0 + row) * K + kel;
    int slot = m0 + row; if (slot > cnt - 1) slot = cnt - 1;
    size_t arow;
    if (MODE == 0) arow = (size_t)toklist[e * BATCH + slot];
    else           arow = (size_t)(off_e + slot);
    aptr[l] = Abase + arow * K + kel;
  }

  f32x4 acc[4][4];
#pragma unroll
  for (int i = 0; i < 4; i++)
#pragma unroll
    for (int j = 0; j < 4; j++) acc[i][j] = {0.f, 0.f, 0.f, 0.f};

  const int lane = tid & 63;
  const int wave = tid >> 6;
  const int wm = (wave >> 1) * 64;
  const int wn = (wave & 1) * 64;
  const int fr = lane & 15;
  const int fc = lane >> 4;
  const unsigned sx = (unsigned)((fr & 7) << 4);

  for (int k0 = 0; k0 < K; k0 += 64) {
    __syncthreads();  // prior compute done before LDS overwrite
#pragma unroll
    for (int l = 0; l < 4; l++)
      __builtin_amdgcn_global_load_lds((gconst_t*)(aptr[l] + k0),
                                       (lds_t*)((char*)At + ldsoff[l]), 16, 0, 0);
#pragma unroll
    for (int l = 0; l < 4; l++)
      __builtin_amdgcn_global_load_lds((gconst_t*)(bptr[l] + k0),
                                       (lds_t*)((char*)Bt + ldsoff[l]), 16, 0, 0);
    __syncthreads();  // compiler drains vmcnt before barrier
#pragma unroll
    for (int ks = 0; ks < 2; ks++) {
      bf16x8 af[4], bv[4];
#pragma unroll
      for (int mi = 0; mi < 4; mi++) {
        unsigned row = (unsigned)(wm + mi * 16 + fr);
        unsigned addr = ((row << 7) + (unsigned)(ks * 64 + fc * 16)) ^ sx;
        af[mi] = *(const bf16x8*)((const char*)At + addr);
      }
#pragma unroll
      for (int ni = 0; ni < 4; ni++) {
        unsigned row = (unsigned)(wn + ni * 16 + fr);
        unsigned addr = ((row << 7) + (unsigned)(ks * 64 + fc * 16)) ^ sx;
        bv[ni] = *(const bf16x8*)((const char*)Bt + addr);
      }
#pragma unroll
      for (int mi = 0; mi < 4; mi++)
#pragma unroll
        for (int ni = 0; ni < 4; ni++)
          acc[mi][ni] = __builtin_amdgcn_mfma_f32_16x16x32_bf16(af[mi], bv[ni], acc[mi][ni], 0, 0, 0);
    }
  }

  // epilogue: C/D layout col=lane&15, row=(lane>>4)*4+reg  [HW-verified m89/m91]
  const int crow = (lane >> 4) * 4;
  const int ccol = lane & 15;
#pragma unroll
  for (int mi = 0; mi < 4; mi++) {
#pragma unroll
    for (int r = 0; r < 4; r++) {
      const int slot = m0 + wm + mi * 16 + crow + r;
      if (slot >= cnt) continue;
      if (MODE == 0) {
        unsigned short* hrow = Hout + (size_t)(off_e + slot) * HID;
#pragma unroll
        for (int ni = 0; ni < 4; ni++) {
          int n = n0 + wn + ni * 16 + ccol;
          float v = acc[mi][ni][r] + bias[n];
          hrow[n] = f2bf(fmaxf(v, 0.f));
        }
      } else {
        const int tok = toklist[e * BATCH + slot];
        float* yrow = Yout + (size_t)tok * OUT_DIM;
#pragma unroll
        for (int ni = 0; ni < 4; ni++) {
          int n = n0 + wn + ni * 16 + ccol;
          yrow[n] = acc[mi][ni][r] + bias[n];
        }
      }
    }
  }
}

extern "C" void kernel_launch(void* const* d_in, const int* in_sizes, int n_in,
                              void* d_out, int out_size, void* d_ws, size_t ws_size,
                              hipStream_t stream) {
  const float* x   = (const float*)d_in[0];
  const float* rw1 = (const float*)d_in[1];
  const float* rb1 = (const float*)d_in[2];
  const float* rw2 = (const float*)d_in[3];
  const float* rb2 = (const float*)d_in[4];
  const float* ew1 = (const float*)d_in[5];
  const float* eb1 = (const float*)d_in[6];
  const float* ew2 = (const float*)d_in[7];
  const float* eb2 = (const float*)d_in[8];
  float* out = (float*)d_out;

  char* ws = (char*)d_ws;
  unsigned short* xb  = (unsigned short*)(ws + XBF_OFF);
  unsigned short* w1t = (unsigned short*)(ws + W1T_OFF);
  unsigned short* w2t = (unsigned short*)(ws + W2T_OFF);
  unsigned short* h   = (unsigned short*)(ws + H_OFF);
  int* counts    = (int*)(ws + META_OFF);
  int* counters2 = counts + 8;
  int* toklist   = counts + 16;
  int* selected  = toklist + NE * BATCH;

  hipMemsetAsync(counts, 0, 64, stream);
  cvt_x_kernel<<<2048, 256, 0, stream>>>(x, xb);
  transpose_cvt<<<dim3(64, 16, 3), 256, 0, stream>>>(ew1, w1t, IN_DIM, HID);
  transpose_cvt<<<dim3(16, 64, 3), 256, 0, stream>>>(ew2, w2t, HID, OUT_DIM);
  router_kernel<<<1024, 128, 0, stream>>>(x, rw1, rb1, rw2, rb2, selected, counts);
  bucket_kernel<<<32, 256, 0, stream>>>(selected, counters2, toklist, counts,
                                        out + (size_t)BATCH * OUT_DIM);
  moe_gemm<0><<<dim3(64, 32, 3), 256, 0, stream>>>(xb, w1t, eb1, h, nullptr, toklist, counts);
  moe_gemm<1><<<dim3(64, 8, 3), 256, 0, stream>>>(h, w2t, eb2, nullptr, out, toklist, counts);
}

// Round 2
// 368.295 us; speedup vs baseline: 1.3817x; 1.3817x over previous
//
#include <hip/hip_runtime.h>
#include <hip/hip_bf16.h>

typedef short bf16x8 __attribute__((ext_vector_type(8)));
typedef float f32x4 __attribute__((ext_vector_type(4)));
typedef __attribute__((address_space(1))) const void gconst_t;
typedef __attribute__((address_space(3))) void lds_t;

#define DEVI __device__ __forceinline__

constexpr int BATCH   = 8192;
constexpr int IN_DIM  = 1024;
constexpr int HID     = 4096;
constexpr int OUT_DIM = 1024;
constexpr int NE      = 3;

// ---- workspace layout (bytes) ----
constexpr size_t XBF_OFF  = 0;                         // x bf16: 16 MB
constexpr size_t W1T_OFF  = 16777216;                  // W1T bf16 [E][HID][IN]: 24 MB
constexpr size_t W2T_OFF  = W1T_OFF + 25165824;        // W2T bf16 [E][OUT][HID]: 24 MB
constexpr size_t H_OFF    = W2T_OFF + 25165824;        // H bf16 grouped rows: 64 MB
constexpr size_t META_OFF = H_OFF + 67108864;          // counts[8], toklist[3*8192]

DEVI unsigned short f2bf(float f) {
  __hip_bfloat16 h = __float2bfloat16(f);
  return *reinterpret_cast<unsigned short*>(&h);
}

// =====================================================================
// Fused preprocessing: router(+bucket) | transpose W1 | transpose W2 | cvt x
// Grid ranges (router first so the compute-heavy blocks start earliest):
//   [0,1024)       router: 8 tokens/block, f32 math, atomic bucket
//   [1024,4096)    transpose+cvt W1 (per expert [1024][4096] -> [4096][1024])
//   [4096,7168)    transpose+cvt W2 (per expert [4096][1024] -> [1024][4096])
//   [7168,7680)    x f32 -> bf16
// =====================================================================
__global__ __launch_bounds__(256) void prep_kernel(
    const float* __restrict__ x, const float* __restrict__ ew1, const float* __restrict__ ew2,
    const float* __restrict__ rw1, const float* __restrict__ rb1,
    const float* __restrict__ rw2, const float* __restrict__ rb2,
    unsigned short* __restrict__ xb, unsigned short* __restrict__ w1t,
    unsigned short* __restrict__ w2t, int* __restrict__ counts, int* __restrict__ toklist) {
  __shared__ float smem[8 * 1024 + 8 * 128];  // router xs[8][1024] + rh[8][128]; transposes alias
  const int b = blockIdx.x;
  const int tid = threadIdx.x;

  if (b < 1024) {
    // ---------------- router ----------------
    const int t0 = b * 8;
    float* xs = smem;             // [8][1024]
    float* rh = smem + 8 * 1024;  // [8][128]
    {
      const float4* src = (const float4*)(x + (size_t)t0 * 1024);
      float4* dstv = (float4*)xs;
      for (int i = tid; i < 2048; i += 256) dstv[i] = src[i];
    }
    __syncthreads();
    const int g = tid >> 7, hcol = tid & 127;
    float acc[4] = {0.f, 0.f, 0.f, 0.f};
    for (int k = 0; k < 1024; k += 4) {
      const float w0 = rw1[(k + 0) * 128 + hcol];
      const float w1v = rw1[(k + 1) * 128 + hcol];
      const float w2v = rw1[(k + 2) * 128 + hcol];
      const float w3v = rw1[(k + 3) * 128 + hcol];
#pragma unroll
      for (int tt = 0; tt < 4; tt++) {
        const float4 xv = *(const float4*)&xs[(g * 4 + tt) * 1024 + k];
        acc[tt] = fmaf(xv.x, w0, acc[tt]);
        acc[tt] = fmaf(xv.y, w1v, acc[tt]);
        acc[tt] = fmaf(xv.z, w2v, acc[tt]);
        acc[tt] = fmaf(xv.w, w3v, acc[tt]);
      }
    }
    const float bb1 = rb1[hcol];
#pragma unroll
    for (int tt = 0; tt < 4; tt++)
      rh[(g * 4 + tt) * 128 + hcol] = fmaxf(acc[tt] + bb1, 0.f);
    __syncthreads();  // xs free after this point
    float* lg = smem; // [8][3]
    if (tid < 24) {
      const int t = tid / 3, e = tid % 3;
      float s = rb2[e];
      for (int j = 0; j < 128; j++) s = fmaf(rh[t * 128 + j], rw2[j * 3 + e], s);
      lg[t * 3 + e] = s;
    }
    __syncthreads();
    if (tid < 8) {
      const float l0 = lg[tid * 3], l1 = lg[tid * 3 + 1], l2 = lg[tid * 3 + 2];
      int sel = 0; float m = l0;
      if (l1 > m) { m = l1; sel = 1; }
      if (l2 > m) { m = l2; sel = 2; }
      const int slot = atomicAdd(&counts[sel], 1);
      toklist[sel * BATCH + slot] = t0 + tid;
    }
  } else if (b < 7168) {
    // ---------------- weight transpose + cvt ----------------
    float (*tile)[65] = (float(*)[65])smem;
    const float* src; unsigned short* dst; int R, C, r0, c0;
    if (b < 4096) {
      const int bb = b - 1024, e = bb / 1024, w = bb % 1024;
      src = ew1 + (size_t)e * 1024 * 4096; dst = w1t + (size_t)e * 4096 * 1024;
      R = 1024; C = 4096; r0 = (w & 15) * 64; c0 = (w >> 4) * 64;
    } else {
      const int bb = b - 4096, e = bb / 1024, w = bb % 1024;
      src = ew2 + (size_t)e * 4096 * 1024; dst = w2t + (size_t)e * 1024 * 4096;
      R = 4096; C = 1024; r0 = (w & 63) * 64; c0 = (w >> 6) * 64;
    }
    const int tr = tid >> 4;
    const int tc = (tid & 15) << 2;
#pragma unroll
    for (int i = 0; i < 4; i++) {
      const int r = tr + i * 16;
      const float4 v = *(const float4*)(src + (size_t)(r0 + r) * C + (c0 + tc));
      tile[r][tc + 0] = v.x; tile[r][tc + 1] = v.y; tile[r][tc + 2] = v.z; tile[r][tc + 3] = v.w;
    }
    __syncthreads();
#pragma unroll
    for (int i = 0; i < 4; i++) {
      const int c = tr + i * 16;
      ushort4 o;
      o.x = f2bf(tile[tc + 0][c]);
      o.y = f2bf(tile[tc + 1][c]);
      o.z = f2bf(tile[tc + 2][c]);
      o.w = f2bf(tile[tc + 3][c]);
      *(ushort4*)(dst + (size_t)(c0 + c) * R + (r0 + tc)) = o;
    }
  } else {
    // ---------------- x -> bf16 ----------------
    const float4* xv4 = (const float4*)x;
    const int total = BATCH * IN_DIM / 4;
    for (int i = (b - 7168) * 256 + tid; i < total; i += 512 * 256) {
      const float4 v = xv4[i];
      ushort4 o;
      o.x = f2bf(v.x); o.y = f2bf(v.y); o.z = f2bf(v.z); o.w = f2bf(v.w);
      ((ushort4*)xb)[i] = o;
    }
  }
}

// =====================================================================
// Grouped bf16 GEMM, 128x128 tile, BK=64, 4 waves, double-buffered LDS,
// raw-barrier prefetch pipeline (loads in flight across the MFMA cluster).
// MODE 0: A = xb gathered via toklist, B = W1T[e], relu(+b1) -> H bf16 (grouped)
// MODE 1: A = H grouped rows,          B = W2T[e], +b2 -> scatter f32 to out
// =====================================================================
template <int MODE>
__global__ __launch_bounds__(256, 2) void moe_gemm(
    const unsigned short* __restrict__ Abase, const unsigned short* __restrict__ Ball,
    const float* __restrict__ biasAll, unsigned short* __restrict__ Hout,
    float* __restrict__ Yout, const int* __restrict__ toklist, const int* __restrict__ counts,
    float* __restrict__ tail) {
  constexpr int N = (MODE == 0) ? HID : OUT_DIM;
  constexpr int K = (MODE == 0) ? IN_DIM : HID;
  constexpr int NT = K / 64;

  if (MODE == 0 && blockIdx.x == 0 && blockIdx.y == 0 && threadIdx.x < NE)
    tail[threadIdx.x] = (float)counts[threadIdx.x];

  // flat M-grid -> (expert, m-block) via device-side prefix over counts
  const int c0 = counts[0], c1 = counts[1], c2 = counts[2];
  const int mb0 = (c0 + 127) >> 7, mb1 = (c1 + 127) >> 7, mb2 = (c2 + 127) >> 7;
  const int bx = blockIdx.x;
  int e, mblk;
  if (bx < mb0) { e = 0; mblk = bx; }
  else if (bx < mb0 + mb1) { e = 1; mblk = bx - mb0; }
  else if (bx < mb0 + mb1 + mb2) { e = 2; mblk = bx - mb0 - mb1; }
  else return;
  const int cnt = (e == 0) ? c0 : (e == 1) ? c1 : c2;
  const int m0 = mblk * 128;
  const int n0 = blockIdx.y * 128;
  const int off_e = (e > 0 ? c0 : 0) + (e > 1 ? c1 : 0);
  const unsigned short* Bmat = Ball + (size_t)e * ((size_t)N * K);
  const float* bias = biasAll + (size_t)e * N;

  __shared__ unsigned short Ab[2][128 * 64];
  __shared__ unsigned short Bb[2][128 * 64];

  const int tid = threadIdx.x;
  // staging: LDS dest linear (o), global source pre-swizzled (p) so readers
  // apply the same XOR (G21 both-sides discipline).
  const unsigned short* aptr[4];
  const unsigned short* bptr[4];
  unsigned ldsoff[4];
#pragma unroll
  for (int l = 0; l < 4; l++) {
    const unsigned o = l * 4096u + (unsigned)tid * 16u;
    const unsigned p = o ^ (((o >> 7) & 7u) << 4);
    const int row = (int)(p >> 7);
    const int kel = (int)((p & 127u) >> 1);
    ldsoff[l] = o;
    bptr[l] = Bmat + (size_t)(n0 + row) * K + kel;
    int slot = m0 + row; if (slot > cnt - 1) slot = cnt - 1;
    const size_t arow = (MODE == 0) ? (size_t)toklist[e * BATCH + slot]
                                    : (size_t)(off_e + slot);
    aptr[l] = Abase + arow * K + kel;
  }

  f32x4 acc[4][4];
#pragma unroll
  for (int i = 0; i < 4; i++)
#pragma unroll
    for (int j = 0; j < 4; j++) acc[i][j] = {0.f, 0.f, 0.f, 0.f};

  const int lane = tid & 63;
  const int wave = tid >> 6;
  const int wm = (wave >> 1) * 64;
  const int wn = (wave & 1) * 64;
  const int fr = lane & 15;
  const int fc = lane >> 4;
  const unsigned sx = (unsigned)((fr & 7) << 4);

  auto STAGE = [&](int buf, int kofs) {
#pragma unroll
    for (int l = 0; l < 4; l++)
      __builtin_amdgcn_global_load_lds((gconst_t*)(aptr[l] + kofs),
                                       (lds_t*)((char*)&Ab[buf][0] + ldsoff[l]), 16, 0, 0);
#pragma unroll
    for (int l = 0; l < 4; l++)
      __builtin_amdgcn_global_load_lds((gconst_t*)(bptr[l] + kofs),
                                       (lds_t*)((char*)&Bb[buf][0] + ldsoff[l]), 16, 0, 0);
  };

  // prologue: stage tile 0, drain, barrier
  STAGE(0, 0);
  asm volatile("s_waitcnt vmcnt(0)" ::: "memory");
  __builtin_amdgcn_s_barrier();

  for (int t = 0; t < NT; ++t) {
    const int cur = t & 1;
    bf16x8 af[2][4], bv[2][4];
#pragma unroll
    for (int ks = 0; ks < 2; ks++) {
#pragma unroll
      for (int m = 0; m < 4; m++) {
        const unsigned row = (unsigned)(wm + m * 16 + fr);
        const unsigned addr = ((row << 7) + (unsigned)(ks * 64 + fc * 16)) ^ sx;
        af[ks][m] = *(const bf16x8*)((const char*)&Ab[cur][0] + addr);
      }
#pragma unroll
      for (int n = 0; n < 4; n++) {
        const unsigned row = (unsigned)(wn + n * 16 + fr);
        const unsigned addr = ((row << 7) + (unsigned)(ks * 64 + fc * 16)) ^ sx;
        bv[ks][n] = *(const bf16x8*)((const char*)&Bb[cur][0] + addr);
      }
    }
    asm volatile("s_waitcnt lgkmcnt(0)" ::: "memory");
    __builtin_amdgcn_sched_barrier(0);
    __builtin_amdgcn_s_barrier();            // R-bar: all waves done reading buf[cur]
    if (t + 1 < NT) STAGE(cur ^ 1, (t + 1) * 64);  // prefetch next tile (in flight)
#pragma unroll
    for (int ks = 0; ks < 2; ks++)
#pragma unroll
      for (int m = 0; m < 4; m++)
#pragma unroll
        for (int n = 0; n < 4; n++)
          acc[m][n] = __builtin_amdgcn_mfma_f32_16x16x32_bf16(af[ks][m], bv[ks][n], acc[m][n], 0, 0, 0);
    if (t + 1 < NT) {
      asm volatile("s_waitcnt vmcnt(0)" ::: "memory");  // own stage loads landed
      __builtin_amdgcn_s_barrier();          // S-bar: all waves' stages landed
    }
  }

  // epilogue: C/D layout col=lane&15, row=(lane>>4)*4+reg  [HW-verified m89/m91]
  const int crow = (lane >> 4) * 4;
  const int ccol = lane & 15;
#pragma unroll
  for (int mi = 0; mi < 4; mi++) {
#pragma unroll
    for (int r = 0; r < 4; r++) {
      const int slot = m0 + wm + mi * 16 + crow + r;
      if (slot >= cnt) continue;
      if (MODE == 0) {
        unsigned short* hrow = Hout + (size_t)(off_e + slot) * HID;
#pragma unroll
        for (int ni = 0; ni < 4; ni++) {
          const int n = n0 + wn + ni * 16 + ccol;
          const float v = acc[mi][ni][r] + bias[n];
          hrow[n] = f2bf(fmaxf(v, 0.f));
        }
      } else {
        const int tok = toklist[e * BATCH + slot];
        float* yrow = Yout + (size_t)tok * OUT_DIM;
#pragma unroll
        for (int ni = 0; ni < 4; ni++) {
          const int n = n0 + wn + ni * 16 + ccol;
          yrow[n] = acc[mi][ni][r] + bias[n];
        }
      }
    }
  }
}

extern "C" void kernel_launch(void* const* d_in, const int* in_sizes, int n_in,
                              void* d_out, int out_size, void* d_ws, size_t ws_size,
                              hipStream_t stream) {
  const float* x   = (const float*)d_in[0];
  const float* rw1 = (const float*)d_in[1];
  const float* rb1 = (const float*)d_in[2];
  const float* rw2 = (const float*)d_in[3];
  const float* rb2 = (const float*)d_in[4];
  const float* ew1 = (const float*)d_in[5];
  const float* eb1 = (const float*)d_in[6];
  const float* ew2 = (const float*)d_in[7];
  const float* eb2 = (const float*)d_in[8];
  float* out = (float*)d_out;

  char* ws = (char*)d_ws;
  unsigned short* xb  = (unsigned short*)(ws + XBF_OFF);
  unsigned short* w1t = (unsigned short*)(ws + W1T_OFF);
  unsigned short* w2t = (unsigned short*)(ws + W2T_OFF);
  unsigned short* h   = (unsigned short*)(ws + H_OFF);
  int* counts  = (int*)(ws + META_OFF);
  int* toklist = counts + 16;
  float* tail = out + (size_t)BATCH * OUT_DIM;

  hipMemsetAsync(counts, 0, 64, stream);
  prep_kernel<<<7680, 256, 0, stream>>>(x, ew1, ew2, rw1, rb1, rw2, rb2,
                                        xb, w1t, w2t, counts, toklist);
  moe_gemm<0><<<dim3(66, 32), 256, 0, stream>>>(xb, w1t, eb1, h, nullptr, toklist, counts, tail);
  moe_gemm<1><<<dim3(66, 8), 256, 0, stream>>>(h, w2t, eb2, nullptr, out, toklist, counts, tail);
}